// Round 24
// baseline (172.405 us; speedup 1.0000x reference)
//
#include <hip/hip_runtime.h>
#include <math.h>

// Hardened single-rounded ops (never contracted/fused by the compiler):
#define FMUL(a,b) __fmul_rn((a),(b))
#define FADD(a,b) __fadd_rn((a),(b))
#define FSUB(a,b) __fsub_rn((a),(b))

#define BB 2048   // batch
#define DD 1024   // feature dim (K)
#define TT 32     // LIF steps
#define TS 64     // tile: 64 rows x 64 cols
#define KB 32     // k per LDS slab (8 float4 k-groups)
#define NSLAB 32
#define HALFS 16  // chunk boundary slab (k=512)

// CONFIRMED golden semantics (r16 band 7; r17-r23 all passed bit-exact):
//   dot = FADD( fmaf-chain(k=0..511), fmaf-chain(k=512..1023) )
//   cur = FADD(dot, bias[e]); rec: m = FSUB(FADD(FMUL(0.9f,m),cur),reset)
//
// r24: 128-thr (2-wave) blocks, 64x64 tile, Mt=4 x Nt=8 per thread
// (12 b128 per 32 quad-FMAs = 0.375 ratio vs r18's 0.5) with r20's
// measured-zero-conflict XOR LDS layouts. Grid 512 -> 2 blocks/CU.
__global__ __launch_bounds__(128) void lif_fused_kernel(
    const float* __restrict__ latent,
    const float* __restrict__ W,
    const float* __restrict__ bias,
    const float* __restrict__ gainp,
    float* __restrict__ out)
{
    // A: idx = row*8 + (g ^ (row&7))      -> read quads = g^(ty&7): 8 distinct, free
    // W: idx = col*8 + (g ^ ((col>>2)&7)) -> read quads = g^tx: 8 distinct, free
    __shared__ float4 As4[2][TS * 8];   // 16 KB
    __shared__ float4 Ws4[2][TS * 8];   // 16 KB

    const int tid = threadIdx.x;     // 0..127
    const int tx = tid & 7;          // col f4-groups: tx (cols tx*4..+3) and tx+8
    const int ty = tid >> 3;         // 0..15: rows ty + 16*i, i<4
    const int e0 = blockIdx.x * TS;
    const int b0 = blockIdx.y * TS;

    // staging: thread stages row lrow, k-groups lh*4+c (c=0..3)
    const int lrow = tid >> 1;       // 0..63
    const int lh   = tid & 1;
    const float* aP = latent + (size_t)(b0 + lrow) * DD + lh * 16;
    const float* wP = W      + (size_t)(e0 + lrow) * DD + lh * 16;

    float4 apf[4], wpf[4];
#pragma unroll
    for (int c = 0; c < 4; ++c) {
        apf[c] = *(const float4*)(aP + c * 4);
        wpf[c] = *(const float4*)(wP + c * 4);
    }

    // acc[i][side][j]: rows ty+16i; side 0 = cols tx*4+j, side 1 = cols 32+tx*4+j
    float acc[4][2][4], tot[4][2][4];
#pragma unroll
    for (int i = 0; i < 4; ++i)
#pragma unroll
        for (int sd = 0; sd < 2; ++sd)
#pragma unroll
            for (int j = 0; j < 4; ++j) acc[i][sd][j] = 0.0f;

    int p = 0;
    for (int s = 0; s < NSLAB; ++s) {
        // stage slab (r20-pattern swizzled stores, measured conflict-free)
#pragma unroll
        for (int c = 0; c < 4; ++c) {
            const int g = lh * 4 + c;
            As4[p][lrow * 8 + (g ^ (lrow & 7))]        = apf[c];
            Ws4[p][lrow * 8 + (g ^ ((lrow >> 2) & 7))] = wpf[c];
        }
        __syncthreads();

        if (s + 1 < NSLAB) {         // prefetch next slab into regs
            const int k0 = (s + 1) * KB;
#pragma unroll
            for (int c = 0; c < 4; ++c) {
                apf[c] = *(const float4*)(aP + k0 + c * 4);
                wpf[c] = *(const float4*)(wP + k0 + c * 4);
            }
        }

        if (s == HALFS) {            // chunk boundary k=512: save S1, restart chain
#pragma unroll
            for (int i = 0; i < 4; ++i)
#pragma unroll
                for (int sd = 0; sd < 2; ++sd)
#pragma unroll
                    for (int j = 0; j < 4; ++j) { tot[i][sd][j] = acc[i][sd][j]; acc[i][sd][j] = 0.0f; }
        }

#pragma unroll
        for (int g = 0; g < 8; ++g) {
            float4 a4[4], wL[4], wR[4];
#pragma unroll
            for (int i = 0; i < 4; ++i)
                a4[i] = As4[p][(ty + 16 * i) * 8 + (g ^ (ty & 7))];
#pragma unroll
            for (int j = 0; j < 4; ++j) {
                wL[j] = Ws4[p][(tx * 4 + j) * 8 + (g ^ tx)];        // (col>>2)&7 = tx
                wR[j] = Ws4[p][(32 + tx * 4 + j) * 8 + (g ^ tx)];   // (col>>2)&7 = tx+8&7 = tx
            }
#pragma unroll
            for (int i = 0; i < 4; ++i) {
#pragma unroll
                for (int j = 0; j < 4; ++j) {
                    float a = acc[i][0][j];
                    a = fmaf(a4[i].x, wL[j].x, a);   // strict ascending k
                    a = fmaf(a4[i].y, wL[j].y, a);
                    a = fmaf(a4[i].z, wL[j].z, a);
                    a = fmaf(a4[i].w, wL[j].w, a);
                    acc[i][0][j] = a;
                    float b = acc[i][1][j];
                    b = fmaf(a4[i].x, wR[j].x, b);
                    b = fmaf(a4[i].y, wR[j].y, b);
                    b = fmaf(a4[i].z, wR[j].z, b);
                    b = fmaf(a4[i].w, wR[j].w, b);
                    acc[i][1][j] = b;
                }
            }
        }
        p ^= 1;
    }

    // cur = FADD(FADD(S1, S2), bias)  (reuse tot as cur)
    float4 bvL = *(const float4*)&bias[e0 + tx * 4];
    float4 bvR = *(const float4*)&bias[e0 + 32 + tx * 4];
#pragma unroll
    for (int i = 0; i < 4; ++i)
#pragma unroll
        for (int j = 0; j < 4; ++j) {
            tot[i][0][j] = FADD(FADD(tot[i][0][j], acc[i][0][j]), ((const float*)&bvL)[j]);
            tot[i][1][j] = FADD(FADD(tot[i][1][j], acc[i][1][j]), ((const float*)&bvR)[j]);
        }

    // hardened f32 LIF recurrence
    float mem[4][2][4];
    int cnt[4][2][4];
#pragma unroll
    for (int i = 0; i < 4; ++i)
#pragma unroll
        for (int sd = 0; sd < 2; ++sd)
#pragma unroll
            for (int j = 0; j < 4; ++j) { mem[i][sd][j] = 0.0f; cnt[i][sd][j] = 0; }

    float* spk = out + (size_t)BB * DD;
    const int colL = e0 + tx * 4;
    const int colR = e0 + 32 + tx * 4;

    for (int t = 0; t < TT; ++t) {
#pragma unroll
        for (int i = 0; i < 4; ++i) {
            const size_t rbase = ((size_t)(b0 + ty + 16 * i) * TT + t) * DD;
            float4 sL, sR;
#pragma unroll
            for (int j = 0; j < 4; ++j) {
                float m = mem[i][0][j];
                float r = (m > 1.0f) ? 1.0f : 0.0f;
                m = FSUB(FADD(FMUL(0.9f, m), tot[i][0][j]), r);
                mem[i][0][j] = m;
                int f = (m > 1.0f) ? 1 : 0;
                cnt[i][0][j] += f;
                ((float*)&sL)[j] = (float)f;

                float m2 = mem[i][1][j];
                float r2 = (m2 > 1.0f) ? 1.0f : 0.0f;
                m2 = FSUB(FADD(FMUL(0.9f, m2), tot[i][1][j]), r2);
                mem[i][1][j] = m2;
                int f2 = (m2 > 1.0f) ? 1 : 0;
                cnt[i][1][j] += f2;
                ((float*)&sR)[j] = (float)f2;
            }
            *(float4*)&spk[rbase + colL] = sL;
            *(float4*)&spk[rbase + colR] = sR;
        }
    }

    // scale = 0.4*sigmoid(gain); updated = relu(latent + scale*mean_t(spikes))
    const float g = gainp[0];
    const float scale = 0.4f * (1.0f / (1.0f + expf(-g)));
#pragma unroll
    for (int i = 0; i < 4; ++i) {
        const size_t rbase = (size_t)(b0 + ty + 16 * i) * DD;
        float4 lvL = *(const float4*)&latent[rbase + colL];
        float4 lvR = *(const float4*)&latent[rbase + colR];
        float4 uL, uR;
#pragma unroll
        for (int j = 0; j < 4; ++j) {
            float vL = FADD(((const float*)&lvL)[j], FMUL(scale, (float)cnt[i][0][j] * 0.03125f));
            float vR = FADD(((const float*)&lvR)[j], FMUL(scale, (float)cnt[i][1][j] * 0.03125f));
            ((float*)&uL)[j] = vL > 0.0f ? vL : 0.0f;
            ((float*)&uR)[j] = vR > 0.0f ? vR : 0.0f;
        }
        *(float4*)&out[rbase + colL] = uL;
        *(float4*)&out[rbase + colR] = uR;
    }

    if (blockIdx.x == 0 && blockIdx.y == 0 && tid == 0)
        out[(size_t)BB * DD + (size_t)BB * TT * DD] = scale;
}

extern "C" void kernel_launch(void* const* d_in, const int* in_sizes, int n_in,
                              void* d_out, int out_size, void* d_ws, size_t ws_size,
                              hipStream_t stream) {
    (void)in_sizes; (void)n_in; (void)d_ws; (void)ws_size; (void)out_size;
    const float* latent = (const float*)d_in[0];
    const float* W      = (const float*)d_in[1];
    const float* bias   = (const float*)d_in[2];
    const float* gain   = (const float*)d_in[3];
    float* out = (float*)d_out;

    dim3 grid(DD / TS, BB / TS);  // (16, 32) = 512 blocks -> 2/CU, 4 waves/CU
    dim3 block(128);              // 2 waves
    lif_fused_kernel<<<grid, block, 0, stream>>>(latent, W, bias, gain, out);
}